// Round 13
// baseline (427.768 us; speedup 1.0000x reference)
//
#include <hip/hip_runtime.h>
#include <cstdint>
#include <cstddef>

typedef unsigned int   u32;
typedef unsigned short u16;
typedef unsigned long long u64;
typedef __attribute__((ext_vector_type(8))) short bf16x8;
typedef __attribute__((ext_vector_type(4))) float f32x4;

__device__ __forceinline__ float bf2f(u32 bits16) { return __uint_as_float(bits16 << 16); }
__device__ __forceinline__ u16 f2bf(float f) {
  u32 u = __float_as_uint(f);
  u = u + 0x7FFFu + ((u >> 16) & 1u);   // round-to-nearest-even
  return (u16)(u >> 16);
}
__device__ __forceinline__ u32 pk(float a, float b) {
  return (u32)f2bf(a) | ((u32)f2bf(b) << 16);
}
__device__ __forceinline__ float lo16(u32 w) { return bf2f(w & 0xFFFFu); }
__device__ __forceinline__ float hi16(u32 w) { return bf2f(w >> 16); }
__device__ __forceinline__ float frcp(float x) { return __builtin_amdgcn_rcpf(x); }
__device__ __forceinline__ float fexp2(float x) { return __builtin_amdgcn_exp2f(x); }  // raw v_exp_f32

#define NL2E   (-1.4426950408889634f)
#define TWOL2E (2.8853900817779268f)
// deg/cnt packed in ONE u64 (native integer atomic, no fp-CAS risk):
// bits 42+: cnt (1 per edge), bits 0..41: deg as 2^26 fixed-point of attr sum.
#define DEGSC    67108864.0f           // 2^26
#define DEGSCINV 1.4901161193847656e-8f
#define DEGMASK  0x3FFFFFFFFFFull      // 42 bits

__device__ __forceinline__ int load_idx(const int* eidx, int is64, long long pos) {
  if (is64) return (int)(((const long long*)eidx)[pos]);
  return eidx[pos];
}

// ---- fused prep (grid 14+NB, 256 thr): all weight tables + zeroing, one dispatch ----
// b0: bc   b1: edge-width detect -> flag   b2: erecI slack + tilectr + tilestat
// b3..4: Wsl2   b5: Wpk   b6..13: Wtg (w=b-6; w 5,7 compute Wc half inline in LDS)
// b>=14: zero dpk (u64)
__global__ void k_prep(const float* Wss, const float* Wsv, const float* Wvs,
                       const float* Wsl, const float* Wvl, const float* Wvv,
                       const float* bvv, const float* bvl,
                       const int* eidx, int E, int* flag, float* bc,
                       u32* Wsl2, u32* Wpk, u16* Wtg,
                       u64* dpk, int* erecI, int* tilestat, int* tilectr,
                       int N, int NB) {
  __shared__ float Wcs[4096];   // 16 KB, used by Wtg blocks w=5,7
  int b = blockIdx.x, tid = threadIdx.x;
  if (b == 0) {
    if (tid < 64) {
      float s = 0.f;
      for (int m = 0; m < 64; ++m) s += Wvl[tid * 128 + m] * bvv[m];
      bc[tid] = s + bvl[tid];
    }
  } else if (b == 1) {
    __shared__ int zc;
    if (tid == 0) zc = 0;
    __syncthreads();
    int n = (E < 1024) ? E : 1024;
    int local = 0;
    for (int i = tid; i < n; i += 256) {
      if (eidx[2 * i + 1] == 0) local++;   // high words if int64 (all 0)
    }
    atomicAdd(&zc, local);
    __syncthreads();
    if (tid == 0) *flag = (zc >= (n >> 1)) ? 1 : 0;
  } else if (b == 2) {
    if (tid < 64) erecI[E + tid] = 0;
    if (tid == 64) *tilectr = 0;
    for (int i = tid; i < NB; i += 256) tilestat[i] = 0;
  } else if (b < 5) {
    for (int i = 0; i < 8; ++i) {
      int o = (b - 3) * 2048 + i * 256 + tid;
      int h = o & 1, c = (o >> 1) & 63, g = o >> 7;
      int k = 4 * g + 2 * h;
      Wsl2[o] = pk(Wsl[c * 128 + k], Wsl[c * 128 + k + 1]);
    }
  } else if (b == 5) {
    for (int i = 0; i < 8; ++i) {
      int o = i * 256 + tid;
      int h = o & 1, c = (o >> 1) & 63, g = o >> 7;
      int k = 4 * g + 2 * h;
      Wpk[o] = pk(Wvl[c * 128 + 64 + k], Wvl[c * 128 + 64 + k + 1]);
    }
  } else if (b < 14) {
    int w = b - 6;
    bool needWc = (w == 5) || (w == 7);   // rows 320-383 (Wc_L), 448-511 (Wc_R)
    if (needWc) {
      int off = (w == 7) ? 64 : 0;
      for (int i = 0; i < 16; ++i) {
        int q = i * 256 + tid;
        int ch = q >> 6, k = q & 63;
        float s = 0.f;
        for (int m = 0; m < 64; ++m) s += Wvl[ch * 128 + m] * Wvv[m * 128 + off + k];
        Wcs[ch * 64 + k] = s;
      }
      __syncthreads();
    }
    for (int i = 0; i < 16; ++i) {
      int p = w * 4096 + i * 256 + tid;
      int r = p >> 6, k = p & 63;
      int g = (r >> 6) & 3, ch = r & 63;
      int src = ch * 128 + ((g & 2) ? 64 : 0) + k;
      float wv;
      if (needWc)       wv = Wcs[ch * 64 + k];
      else if (r < 256) wv = (g & 1) ? Wsv[src] : Wss[src];
      else              wv = Wvs[src];
      u16 h = f2bf(wv);
      Wtg[r * 128 + k] = h;
      Wtg[r * 128 + 64 + k] = f2bf(wv - bf2f(h));
    }
  } else {
    int idx = (b - 14) * 256 + tid;
    if (idx < N) dpk[idx] = 0ull;
  }
}

// ---- single-pass decoupled-lookback scan (wave-parallel lookback) ----
// tilestat[t] packs (flag<<30)|value, value<2^30: flag 1=aggregate, 2=prefix.
__global__ void k_scan(const u64* dpk, float* dis, int* rowptr, int* cursor,
                       int* tilestat, int* tilectr, int N, int E) {
  __shared__ int lds[256];
  __shared__ int sTile, sPrefix;
  int tid = threadIdx.x;
  if (tid == 0) sTile = atomicAdd(tilectr, 1);
  __syncthreads();
  int tile = sTile;
  int idx = tile * 256 + tid;
  int c = 0;
  if (idx < N) {
    u64 p = dpk[idx];
    c = (int)(p >> 42);
    float dg = (float)(p & DEGMASK) * DEGSCINV;
    dis[idx] = (dg > 0.f) ? rsqrtf(dg) : 0.f;
  }
  lds[tid] = c;
  __syncthreads();
  for (int off = 1; off < 256; off <<= 1) {
    int t = (tid >= off) ? lds[tid - off] : 0;
    __syncthreads();
    lds[tid] += t;
    __syncthreads();
  }
  int incl = lds[tid];
  int aggregate = lds[255];
  if (tile == 0) {
    if (tid == 0) {
      atomicExch(&tilestat[0], (2 << 30) | aggregate);
      rowptr[N] = E;
      sPrefix = 0;
    }
  } else {
    if (tid == 0) atomicExch(&tilestat[tile], (1 << 30) | aggregate);
    if (tid < 64) {
      int pred = tile - 1 - tid;
      int excl;
      while (true) {
        int s = (pred >= 0) ? atomicAdd(&tilestat[pred], 0) : (2 << 30);
        u32 fl = (u32)s >> 30;
        unsigned long long pfx = __ballot(fl == 2);
        unsigned long long unp = __ballot(fl == 0);
        int l1 = pfx ? (__ffsll((long long)pfx) - 1) : 64;
        int l0 = unp ? (__ffsll((long long)unp) - 1) : 64;
        if (l1 < 64 && l0 > l1) {
          int v = (tid <= l1) ? (s & 0x3FFFFFFF) : 0;
          #pragma unroll
          for (int o = 32; o > 0; o >>= 1) v += __shfl_xor(v, o, 64);
          excl = v;
          break;
        }
      }
      if (tid == 0) {
        sPrefix = excl;
        atomicExch(&tilestat[tile], (2 << 30) | (excl + aggregate));
      }
    }
  }
  __syncthreads();
  int exclPrefix = sPrefix;
  if (idx < N) {
    int o = exclPrefix + incl - c;
    rowptr[idx] = o;
    cursor[idx] = o;
  }
}

// ---- shared gemm body (v7 MFMA node GEMM, see r7 notes) ----
__device__ __forceinline__ void gemm_body(
    u32* smem, int tid, int nb,
    const float* __restrict__ scalar, const float* __restrict__ vector,
    const u16* __restrict__ Wtg,
    uint4* __restrict__ rec_i4, uint4* __restrict__ rec_j4, int N) {
  u16*   Ax = (u16*)smem;
  float* Ep = (float*)smem;
  int lane = tid & 63, wv = tid >> 6;

  // ---- stage A: thread t: row = t>>2, 16 k's; convert fp32 -> bf16 hi/lo ----
  {
    int srow = tid >> 2, skq = tid & 3;
    const float* sp;
    int snode;
    if (srow < 32) { snode = nb + srow; sp = scalar + (size_t)snode * 64 + skq * 16; }
    else {
      int d = (srow - 32) >> 5, nl2 = (srow - 32) & 31;
      snode = nb + nl2;
      sp = vector + (size_t)snode * 192 + d * 64 + skq * 16;
    }
    bool valid = snode < N;
    u16 hi[16], lo[16];
    #pragma unroll
    for (int q = 0; q < 4; ++q) {
      float4 v = valid ? *(const float4*)(sp + 4 * q) : make_float4(0.f, 0.f, 0.f, 0.f);
      float xs[4] = {v.x, v.y, v.z, v.w};
      #pragma unroll
      for (int j = 0; j < 4; ++j) {
        u16 h = f2bf(xs[j]);
        hi[4 * q + j] = h;
        lo[4 * q + j] = f2bf(xs[j] - bf2f(h));
      }
    }
    int rs = srow & 7;
    #pragma unroll
    for (int c = 0; c < 2; ++c) {
      int lc = 2 * skq + c;
      uint4 wh, wl;
      wh.x = (u32)hi[8*c+0] | ((u32)hi[8*c+1] << 16);
      wh.y = (u32)hi[8*c+2] | ((u32)hi[8*c+3] << 16);
      wh.z = (u32)hi[8*c+4] | ((u32)hi[8*c+5] << 16);
      wh.w = (u32)hi[8*c+6] | ((u32)hi[8*c+7] << 16);
      wl.x = (u32)lo[8*c+0] | ((u32)lo[8*c+1] << 16);
      wl.y = (u32)lo[8*c+2] | ((u32)lo[8*c+3] << 16);
      wl.z = (u32)lo[8*c+4] | ((u32)lo[8*c+5] << 16);
      wl.w = (u32)lo[8*c+6] | ((u32)lo[8*c+7] << 16);
      *(uint4*)(Ax + srow * 128 + (lc ^ rs) * 8)        = wh;
      *(uint4*)(Ax + srow * 128 + ((8 + lc) ^ rs) * 8)  = wl;
    }
  }
  __syncthreads();

  // ---- MFMA main loop ----
  int c0 = wv * 32;
  int bl = lane & 15, bh = lane >> 4;
  f32x4 acc[8][2];
  #pragma unroll
  for (int mt = 0; mt < 8; ++mt)
    #pragma unroll
    for (int nt = 0; nt < 2; ++nt)
      acc[mt][nt] = (f32x4){0.f, 0.f, 0.f, 0.f};

  #pragma unroll
  for (int kh = 0; kh < 2; ++kh) {
    int k0 = kh * 32;
    bf16x8 Bh[2][2], Bl[2][2];
    #pragma unroll
    for (int rg = 0; rg < 2; ++rg)
      #pragma unroll
      for (int nt = 0; nt < 2; ++nt) {
        size_t rr = (size_t)(rg * 256 + c0 + nt * 16 + bl) * 128 + k0 + bh * 8;
        Bh[rg][nt] = *(const bf16x8*)(Wtg + rr);
        Bl[rg][nt] = *(const bf16x8*)(Wtg + rr + 64);
      }
    #pragma unroll
    for (int mt = 0; mt < 8; ++mt) {
      int row = mt * 16 + bl;
      int ch = (k0 >> 3) + bh, rs = row & 7;
      bf16x8 Ah = *(const bf16x8*)(Ax + row * 128 + (ch ^ rs) * 8);
      bf16x8 Al = *(const bf16x8*)(Ax + row * 128 + ((8 + ch) ^ rs) * 8);
      int rg = (mt < 2) ? 0 : 1;
      #pragma unroll
      for (int nt = 0; nt < 2; ++nt) {
        f32x4 a = acc[mt][nt];
        a = __builtin_amdgcn_mfma_f32_16x16x32_bf16(Ah, Bh[rg][nt], a, 0, 0, 0);
        a = __builtin_amdgcn_mfma_f32_16x16x32_bf16(Al, Bh[rg][nt], a, 0, 0, 0);
        a = __builtin_amdgcn_mfma_f32_16x16x32_bf16(Ah, Bl[rg][nt], a, 0, 0, 0);
        acc[mt][nt] = a;
      }
    }
  }

  // ---- epilogue: 4 passes (Gs, v0, v1, v2) through 32KB stage, pack uint4 ----
  int ech = tid & 63, eng = tid >> 6;
  uint4 oi[4], oj[4];
  #pragma unroll
  for (int pg = 0; pg < 4; ++pg) {
    __syncthreads();
    #pragma unroll
    for (int mm = 0; mm < 2; ++mm) {
      int mt = 2 * pg + mm;
      #pragma unroll
      for (int nt = 0; nt < 2; ++nt)
        #pragma unroll
        for (int r = 0; r < 4; ++r) {
          int rl = mm * 16 + bh * 4 + r;
          Ep[rl * 256 + c0 + nt * 16 + bl] = acc[mt][nt][r];
        }
    }
    __syncthreads();
    #pragma unroll
    for (int q = 0; q < 4; ++q) {
      int nl2 = eng + 8 * q;
      float vi0 = Ep[nl2 * 256 + ech];
      float vi1 = Ep[nl2 * 256 + 64 + ech];
      float vj0 = Ep[nl2 * 256 + 128 + ech];
      float vj1 = Ep[nl2 * 256 + 192 + ech];
      if (pg == 0) {
        oi[q].x = pk(vi0, vi1);                  oj[q].x = pk(vj0, vj1);
      } else if (pg == 1) {
        oi[q].y = (u32)f2bf(vi0);                oj[q].y = (u32)f2bf(vj0);
        oi[q].z = (u32)f2bf(vi1) << 16;          oj[q].z = (u32)f2bf(vj1) << 16;
      } else if (pg == 2) {
        oi[q].y |= (u32)f2bf(vi0) << 16;         oj[q].y |= (u32)f2bf(vj0) << 16;
        oi[q].w = (u32)f2bf(vi1);                oj[q].w = (u32)f2bf(vj1);
      } else {
        oi[q].z |= (u32)f2bf(vi0);               oj[q].z |= (u32)f2bf(vj0);
        oi[q].w |= (u32)f2bf(vi1) << 16;         oj[q].w |= (u32)f2bf(vj1) << 16;
      }
    }
  }
  #pragma unroll
  for (int q = 0; q < 4; ++q) {
    int node = nb + eng + 8 * q;
    if (node < N) {
      rec_i4[(size_t)node * 64 + ech] = oi[q];
      rec_j4[(size_t)node * 64 + ech] = oj[q];
    }
  }
}

// ---- fused kernel A: gemm first half + degree atomics (u64, native) ----
__global__ __launch_bounds__(512, 4) void k_gemm_deg(
    const float* __restrict__ scalar, const float* __restrict__ vector,
    const u16* __restrict__ Wtg,
    uint4* __restrict__ rec_i4, uint4* __restrict__ rec_j4, int N, int GB1,
    const int* __restrict__ eidx, const int* __restrict__ flag,
    const float* __restrict__ attr, u64* __restrict__ dpk, int E) {
  __shared__ u32 smem[8192];
  int tid = threadIdx.x;
  if ((int)blockIdx.x >= GB1) {
    int e = ((int)blockIdx.x - GB1) * 512 + tid;
    if (e < E) {
      int is64 = *flag;
      int col = load_idx(eidx, is64, (long long)E + e);
      u64 val = (1ull << 42) | (u64)(attr[e] * DEGSC);
      atomicAdd(&dpk[col], val);
    }
    return;
  }
  gemm_body(smem, tid, (int)blockIdx.x * 32, scalar, vector, Wtg, rec_i4, rec_j4, N);
}

// ---- fused kernel B: gemm second half + CSR fill ----
__global__ __launch_bounds__(512, 4) void k_gemm_fill(
    const float* __restrict__ scalar, const float* __restrict__ vector,
    const u16* __restrict__ Wtg,
    uint4* __restrict__ rec_i4, uint4* __restrict__ rec_j4, int N, int GB1, int GB2,
    const int* __restrict__ eidx, const int* __restrict__ flag,
    const float* __restrict__ attr, const float* __restrict__ dis,
    const float* __restrict__ pos, int* __restrict__ cursor,
    float4* __restrict__ erecA, int* __restrict__ erecI, int E) {
  __shared__ u32 smem[8192];
  int tid = threadIdx.x;
  if ((int)blockIdx.x >= GB2) {
    int e = ((int)blockIdx.x - GB2) * 512 + tid;
    if (e < E) {
      int is64 = *flag;
      int r  = load_idx(eidx, is64, e);
      int cl = load_idx(eidx, is64, (long long)E + e);
      float wr = dis[r] * attr[e];
      float dx = pos[cl * 3 + 0] - pos[r * 3 + 0];
      float dy = pos[cl * 3 + 1] - pos[r * 3 + 1];
      float dz = pos[cl * 3 + 2] - pos[r * 3 + 2];
      int p = atomicAdd(&cursor[cl], 1);
      erecA[p] = make_float4(wr, dx, dy, dz);
      erecI[p] = r;
    }
    return;
  }
  gemm_body(smem, tid, (GB1 + (int)blockIdx.x) * 32, scalar, vector, Wtg, rec_i4, rec_j4, N);
}

// Fused hot kernel: one wave per node, wave-uniform scalar edge metadata,
// 2-edge unrolled loop with double prefetch, in-wave epilogue matvecs.
// Vector head fused across d (one pass over sWv, 3 accumulators).
__global__ __launch_bounds__(512) void k_edges(
    const u16* __restrict__ rec_i, const u16* __restrict__ rec_j,
    const float4* __restrict__ erecA, const int* __restrict__ erecI,
    const int* __restrict__ rowptr, const float* __restrict__ dis,
    const float* __restrict__ scalar, const float* __restrict__ vector,
    const float* __restrict__ bss, const float* __restrict__ bvs,
    const float* __restrict__ bsv, const float* __restrict__ bsl,
    const u32* __restrict__ Wsl2g, const u32* __restrict__ Wpkg,
    const float* __restrict__ bcg,
    float* __restrict__ out_s, float* __restrict__ out_v, int N) {
  __shared__ u32 sWsl[4096];        // 16 KB
  __shared__ u32 sWv[2048];         // 8 KB  (Wvl_right only)
  __shared__ float sStage[8 * 192]; // 6 KB, wave-private epilogue stage
  int tid = threadIdx.x, lane = tid & 63, wv = tid >> 6;
  for (int o = tid; o < 4096; o += 512) sWsl[o] = Wsl2g[o];
  for (int o = tid; o < 2048; o += 512) sWv[o] = Wpkg[o];
  __syncthreads();   // the only block barrier

  int node = __builtin_amdgcn_readfirstlane((int)(blockIdx.x * 8) + wv);
  if (node >= N) node = N - 1;

  uint4 riv = *(const uint4*)(rec_i + ((size_t)node << 9) + lane * 8);
  float aiB  = lo16(riv.x) + bss[lane];
  float KciB = TWOL2E * (hi16(riv.x) + bsv[lane]);
  float Bvs  = bvs[lane];
  float bib0 = lo16(riv.y) + Bvs;
  float bib1 = hi16(riv.y) + Bvs;
  float bib2 = lo16(riv.z) + Bvs;
  float Pi0  = hi16(riv.z), Pi1 = lo16(riv.w), Pi2 = hi16(riv.w);
  float bsl_c = bsl[lane], bc_c = bcg[lane];
  float disc = dis[node];

  float us = 0, uv = 0, t0 = 0, t1 = 0, t2 = 0, g0 = 0, g1 = 0, g2 = 0, wa = 0;
  int rp = rowptr[node], re = rowptr[node + 1];
  u32 lane16 = (u32)lane << 4;
  const char* rjb = (const char*)rec_j;

  // erecI has 64 zeroed ints of slack past E -> prefetch reads always valid
  u32 ra = (u32)erecI[rp];
  u32 rb = (u32)erecI[rp + 1];
  uint4 pre0 = *(const uint4*)(rjb + ((ra << 10) + lane16));
  uint4 pre1 = *(const uint4*)(rjb + ((rb << 10) + lane16));
  int p = rp;
  #define EDGE_MATH(CUR, EV)                                                  \
    {                                                                         \
      float nrm = EV.x, dx = EV.y, dy = EV.z, dz = EV.w;                      \
      float aj  = lo16(CUR.x), cj  = hi16(CUR.x);                             \
      float bj0 = lo16(CUR.y), bj1 = hi16(CUR.y), bj2 = lo16(CUR.z);          \
      float rj0 = hi16(CUR.z), rj1 = lo16(CUR.w), rj2 = hi16(CUR.w);          \
      float xs  = aiB + aj;                                                   \
      float s2s = xs * frcp(1.f + fexp2(xs * NL2E));                          \
      float yv  = (bib0 + bj0) * dx;                                          \
      yv = fmaf(bib1 + bj1, dy, yv);                                          \
      yv = fmaf(bib2 + bj2, dz, yv);                                          \
      float v2s = yv * frcp(1.f + fexp2(yv * NL2E));                          \
      float qh  = fmaf(TWOL2E, cj, KciB);                                     \
      float th0 = fmaf(-2.f, frcp(1.f + fexp2(qh * dx)), 1.f);                \
      float th1 = fmaf(-2.f, frcp(1.f + fexp2(qh * dy)), 1.f);                \
      float th2 = fmaf(-2.f, frcp(1.f + fexp2(qh * dz)), 1.f);                \
      us = fmaf(nrm, s2s, us); uv = fmaf(nrm, v2s, uv);                       \
      t0 = fmaf(nrm, th0, t0); t1 = fmaf(nrm, th1, t1); t2 = fmaf(nrm, th2, t2);\
      g0 = fmaf(nrm, rj0, g0); g1 = fmaf(nrm, rj1, g1); g2 = fmaf(nrm, rj2, g2);\
      wa += nrm;                                                              \
    }
  for (; p + 1 < re; p += 2) {
    uint4 cur0 = pre0, cur1 = pre1;
    u32 rn0 = (u32)erecI[p + 2];
    u32 rn1 = (u32)erecI[p + 3];
    pre0 = *(const uint4*)(rjb + ((rn0 << 10) + lane16));
    pre1 = *(const uint4*)(rjb + ((rn1 << 10) + lane16));
    float4 e0 = erecA[p];
    float4 e1 = erecA[p + 1];
    EDGE_MATH(cur0, e0)
    EDGE_MATH(cur1, e1)
  }
  if (p < re) {
    uint4 cur0 = pre0;
    float4 e0 = erecA[p];
    EDGE_MATH(cur0, e0)
  }
  #undef EDGE_MATH

  // scale by the wave-uniform dis[node] (hoisted out of per-edge nrm)
  us *= disc; uv *= disc;
  t0 *= disc; t1 *= disc; t2 *= disc;
  g0 *= disc; g1 *= disc; g2 *= disc;
  wa *= disc;

  // ---- epilogue: scalar head (wave-local, no block barrier) ----
  float* mys = &sStage[wv * 192];
  mys[lane] = us; mys[64 + lane] = uv;
  __threadfence_block();
  float acc = wa * bsl_c;
  #pragma unroll
  for (int g = 0; g < 32; ++g) {
    float4 u = *(const float4*)&mys[4 * g];
    uint2 w = *(const uint2*)&sWsl[(g * 64 + lane) * 2];
    acc = fmaf(u.x, lo16(w.x), acc);
    acc = fmaf(u.y, hi16(w.x), acc);
    acc = fmaf(u.z, lo16(w.y), acc);
    acc = fmaf(u.w, hi16(w.y), acc);
  }
  size_t so = ((size_t)node << 6) + lane;
  out_s[so] = acc * frcp(1.f + fexp2(acc * NL2E)) + scalar[so];

  // ---- epilogue: vector head, d-fused (one pass over sWv, 3 accumulators) ----
  __threadfence_block();
  mys[lane] = t0; mys[64 + lane] = t1; mys[128 + lane] = t2;
  __threadfence_block();
  float a20 = fmaf(wa, bc_c + Pi0, g0);
  float a21 = fmaf(wa, bc_c + Pi1, g1);
  float a22 = fmaf(wa, bc_c + Pi2, g2);
  #pragma unroll
  for (int g = 0; g < 16; ++g) {
    float4 u0 = *(const float4*)&mys[4 * g];
    float4 u1 = *(const float4*)&mys[64 + 4 * g];
    float4 u2 = *(const float4*)&mys[128 + 4 * g];
    uint2 w = *(const uint2*)&sWv[(g * 64 + lane) * 2];
    float w0 = lo16(w.x), w1 = hi16(w.x), w2 = lo16(w.y), w3 = hi16(w.y);
    a20 = fmaf(u0.x, w0, a20); a20 = fmaf(u0.y, w1, a20);
    a20 = fmaf(u0.z, w2, a20); a20 = fmaf(u0.w, w3, a20);
    a21 = fmaf(u1.x, w0, a21); a21 = fmaf(u1.y, w1, a21);
    a21 = fmaf(u1.z, w2, a21); a21 = fmaf(u1.w, w3, a21);
    a22 = fmaf(u2.x, w0, a22); a22 = fmaf(u2.y, w1, a22);
    a22 = fmaf(u2.z, w2, a22); a22 = fmaf(u2.w, w3, a22);
  }
  float a2v[3] = {a20, a21, a22};
  #pragma unroll
  for (int d = 0; d < 3; ++d) {
    size_t vo = (((size_t)node * 3 + d) << 6) + lane;
    float th = fmaf(-2.f, frcp(1.f + fexp2(TWOL2E * a2v[d])), 1.f);
    out_v[vo] = th + vector[vo];
  }
}

extern "C" void kernel_launch(void* const* d_in, const int* in_sizes, int n_in,
                              void* d_out, int out_size, void* d_ws, size_t ws_size,
                              hipStream_t stream) {
  const float* scalar   = (const float*)d_in[0];
  const float* vector   = (const float*)d_in[1];
  const float* position = (const float*)d_in[2];
  const int*   eidx     = (const int*)d_in[3];
  const float* attr     = (const float*)d_in[4];
  const float* Wss = (const float*)d_in[5];
  const float* bss = (const float*)d_in[6];
  const float* Wvs = (const float*)d_in[7];
  const float* bvs = (const float*)d_in[8];
  const float* Wsl = (const float*)d_in[9];
  const float* bsl = (const float*)d_in[10];
  const float* Wsv = (const float*)d_in[11];
  const float* bsv = (const float*)d_in[12];
  const float* Wvv = (const float*)d_in[13];
  const float* bvv = (const float*)d_in[14];
  const float* Wvl = (const float*)d_in[15];
  const float* bvl = (const float*)d_in[16];

  int N = in_sizes[0] / 64;
  int E = in_sizes[4];
  int NB = (N + 255) / 256;   // scan tiles

  char* wsb = (char*)d_ws;
  size_t off = 0;
  auto alloc = [&](size_t bytes) -> char* {
    char* p = wsb + off;
    off += (bytes + 255) & ~(size_t)255;
    return p;
  };
  u64*    dpk    = (u64*)alloc((size_t)N * 8);
  int*    rowptr = (int*)alloc((size_t)(N + 1) * 4);
  int*    cursor = (int*)alloc((size_t)N * 4);
  float*  dis    = (float*)alloc((size_t)N * 4);
  int*    tilestat = (int*)alloc((size_t)NB * 4);
  int*    tilectr  = (int*)alloc(4);
  float4* erecA  = (float4*)alloc((size_t)E * 16);
  int*    erecI  = (int*)alloc((size_t)(E + 64) * 4);   // +slack for prefetch reads
  u16*    rec_i  = (u16*)alloc((size_t)N * 512 * 2);
  u16*    rec_j  = (u16*)alloc((size_t)N * 512 * 2);
  u16*    Wtg    = (u16*)alloc(512 * 128 * 2);          // 128 KB split-bf16 W^T
  u32*    Wsl2   = (u32*)alloc(4096 * 4);
  u32*    Wpk    = (u32*)alloc(2048 * 4);
  float*  bc     = (float*)alloc(64 * 4);
  int*    flag   = (int*)alloc(4);
  (void)ws_size; (void)n_in; (void)out_size;

  int GB  = (N + 31) / 32;    // total gemm blocks
  int GB1 = GB / 2;           // gemm blocks in kernel A (with deg)
  int GB2 = GB - GB1;         // gemm blocks in kernel B (with fill)
  int DB  = (E + 511) / 512;  // deg/fill blocks (512 thr each)

  k_prep<<<14 + NB, 256, 0, stream>>>(Wss, Wsv, Wvs, Wsl, Wvl, Wvv, bvv, bvl,
                                      eidx, E, flag, bc, Wsl2, Wpk, Wtg,
                                      dpk, erecI, tilestat, tilectr, N, NB);
  k_gemm_deg<<<GB1 + DB, 512, 0, stream>>>(scalar, vector, Wtg,
                                           (uint4*)rec_i, (uint4*)rec_j, N, GB1,
                                           eidx, flag, attr, dpk, E);
  k_scan<<<NB, 256, 0, stream>>>(dpk, dis, rowptr, cursor, tilestat, tilectr, N, E);
  k_gemm_fill<<<GB2 + DB, 512, 0, stream>>>(scalar, vector, Wtg,
                                            (uint4*)rec_i, (uint4*)rec_j, N, GB1, GB2,
                                            eidx, flag, attr, dis, position, cursor,
                                            erecA, erecI, E);
  k_edges<<<(N + 7) / 8, 512, 0, stream>>>(rec_i, rec_j, erecA, erecI, rowptr, dis,
                                           scalar, vector, bss, bvs, bsv, bsl,
                                           Wsl2, Wpk, bc,
                                           (float*)d_out, (float*)d_out + (size_t)N * 64, N);
}

// Round 14
// 398.480 us; speedup vs baseline: 1.0735x; 1.0735x over previous
//
#include <hip/hip_runtime.h>
#include <cstdint>
#include <cstddef>

typedef unsigned int   u32;
typedef unsigned short u16;
typedef __attribute__((ext_vector_type(8))) short bf16x8;
typedef __attribute__((ext_vector_type(4))) float f32x4;

__device__ __forceinline__ float bf2f(u32 bits16) { return __uint_as_float(bits16 << 16); }
__device__ __forceinline__ u16 f2bf(float f) {
  u32 u = __float_as_uint(f);
  u = u + 0x7FFFu + ((u >> 16) & 1u);   // round-to-nearest-even
  return (u16)(u >> 16);
}
__device__ __forceinline__ u32 pk(float a, float b) {
  return (u32)f2bf(a) | ((u32)f2bf(b) << 16);
}
__device__ __forceinline__ float lo16(u32 w) { return bf2f(w & 0xFFFFu); }
__device__ __forceinline__ float hi16(u32 w) { return bf2f(w >> 16); }
__device__ __forceinline__ float frcp(float x) { return __builtin_amdgcn_rcpf(x); }
__device__ __forceinline__ float fexp2(float x) { return __builtin_amdgcn_exp2f(x); }  // raw v_exp_f32

#define NL2E   (-1.4426950408889634f)
#define TWOL2E (2.8853900817779268f)
#define CNTSC  1073741824.0            // 2^30: cnt encoded above deg in one double

__device__ __forceinline__ int load_idx(const int* eidx, int is64, long long pos) {
  if (is64) return (int)(((const long long*)eidx)[pos]);
  return eidx[pos];
}

// ---- prep stage 1 (grid 35 + ceil(N/256)) ----
// b<32: WcTmp = Wvl_left @ Wvv   b32: edge-width detect   b33: bc
// b34: zero erecI slack + scan tilestat/tilectr   b>=35: zero dpk
__global__ void k_prep1(const float* Wvl, const float* Wvv,
                        const float* bvv, const float* bvl,
                        const int* eidx, int E, int* flag,
                        float* WcTmp, float* bc,
                        double* dpk, int* erecI, int* tilestat, int* tilectr,
                        int N, int NB) {
  int b = blockIdx.x, tid = threadIdx.x;
  if (b < 32) {
    int c = 2 * b + (tid >> 7), kk = tid & 127;
    float s = 0.f;
    for (int m = 0; m < 64; ++m) s += Wvl[c * 128 + m] * Wvv[m * 128 + kk];
    WcTmp[c * 128 + kk] = s;
  } else if (b == 32) {
    __shared__ int zc;
    if (tid == 0) zc = 0;
    __syncthreads();
    int n = (E < 1024) ? E : 1024;
    int local = 0;
    for (int i = tid; i < n; i += 256) {
      if (eidx[2 * i + 1] == 0) local++;   // high words if int64 (all 0)
    }
    atomicAdd(&zc, local);
    __syncthreads();
    if (tid == 0) *flag = (zc >= (n >> 1)) ? 1 : 0;
  } else if (b == 33) {
    if (tid < 64) {
      float s = 0.f;
      for (int m = 0; m < 64; ++m) s += Wvl[tid * 128 + m] * bvv[m];
      bc[tid] = s + bvl[tid];
    }
  } else if (b == 34) {
    if (tid < 64) erecI[E + tid] = 0;
    if (tid == 64) *tilectr = 0;
    for (int i = tid; i < NB; i += 256) tilestat[i] = 0;
  } else {
    int idx = (b - 35) * 256 + tid;
    if (idx < N) dpk[idx] = 0.0;
  }
}

// ---- prep stage 2 (grid 11) ----
// b0..1: Wsl2 bf16 table; b2: Wpk; b3..10: Wtg split-bf16 W^T for the MFMA GEMM.
__global__ void k_prep2(const float* Wss, const float* Wsv, const float* Wvs,
                        const float* Wsl, const float* Wvl, const float* WcTmp,
                        u32* Wsl2, u32* Wpk, u16* Wtg) {
  int b = blockIdx.x, tid = threadIdx.x;
  if (b < 2) {
    for (int i = 0; i < 8; ++i) {
      int o = b * 2048 + i * 256 + tid;
      int h = o & 1, c = (o >> 1) & 63, g = o >> 7;
      int k = 4 * g + 2 * h;
      Wsl2[o] = pk(Wsl[c * 128 + k], Wsl[c * 128 + k + 1]);
    }
  } else if (b == 2) {
    for (int i = 0; i < 8; ++i) {
      int o = i * 256 + tid;
      int h = o & 1, c = (o >> 1) & 63, g = o >> 7;
      int k = 4 * g + 2 * h;
      Wpk[o] = pk(Wvl[c * 128 + 64 + k], Wvl[c * 128 + 64 + k + 1]);
    }
  } else {
    for (int i = 0; i < 16; ++i) {
      int p = (b - 3) * 4096 + i * 256 + tid;   // 0..32767
      int r = p >> 6, k = p & 63;
      int g = (r >> 6) & 3, ch = r & 63;
      int src = ch * 128 + ((g & 2) ? 64 : 0) + k;
      float w;
      if (r < 256) w = (g & 1) ? Wsv[src] : Wss[src];
      else         w = (g & 1) ? WcTmp[src] : Wvs[src];
      u16 h = f2bf(w);
      Wtg[r * 128 + k] = h;
      Wtg[r * 128 + 64 + k] = f2bf(w - bf2f(h));
    }
  }
}

// ---- single-pass decoupled-lookback scan (wave-parallel lookback) ----
// tilestat[t] packs (flag<<30)|value, value<2^30: flag 1=aggregate, 2=prefix.
__global__ void k_scan(const double* dpk, float* dis, int* rowptr, int* cursor,
                       int* tilestat, int* tilectr, int N, int E) {
  __shared__ int lds[256];
  __shared__ int sTile, sPrefix;
  int tid = threadIdx.x;
  if (tid == 0) sTile = atomicAdd(tilectr, 1);
  __syncthreads();
  int tile = sTile;
  int idx = tile * 256 + tid;
  int c = 0;
  if (idx < N) {
    double p = dpk[idx];
    c = (int)(p * (1.0 / CNTSC));
    float dg = (float)(p - (double)c * CNTSC);
    dis[idx] = (dg > 0.f) ? rsqrtf(dg) : 0.f;
  }
  lds[tid] = c;
  __syncthreads();
  for (int off = 1; off < 256; off <<= 1) {
    int t = (tid >= off) ? lds[tid - off] : 0;
    __syncthreads();
    lds[tid] += t;
    __syncthreads();
  }
  int incl = lds[tid];
  int aggregate = lds[255];
  if (tile == 0) {
    if (tid == 0) {
      atomicExch(&tilestat[0], (2 << 30) | aggregate);
      rowptr[N] = E;
      sPrefix = 0;
    }
  } else {
    if (tid == 0) atomicExch(&tilestat[tile], (1 << 30) | aggregate);
    if (tid < 64) {
      int pred = tile - 1 - tid;
      int excl;
      while (true) {
        int s = (pred >= 0) ? atomicAdd(&tilestat[pred], 0) : (2 << 30);
        u32 fl = (u32)s >> 30;
        unsigned long long pfx = __ballot(fl == 2);
        unsigned long long unp = __ballot(fl == 0);
        int l1 = pfx ? (__ffsll((long long)pfx) - 1) : 64;
        int l0 = unp ? (__ffsll((long long)unp) - 1) : 64;
        if (l1 < 64 && l0 > l1) {
          int v = (tid <= l1) ? (s & 0x3FFFFFFF) : 0;
          #pragma unroll
          for (int o = 32; o > 0; o >>= 1) v += __shfl_xor(v, o, 64);
          excl = v;
          break;
        }
      }
      if (tid == 0) {
        sPrefix = excl;
        atomicExch(&tilestat[tile], (2 << 30) | (excl + aggregate));
      }
    }
  }
  __syncthreads();
  int exclPrefix = sPrefix;
  if (idx < N) {
    int o = exclPrefix + incl - c;
    rowptr[idx] = o;
    cursor[idx] = o;
  }
}

// CSR fill: erecA[p]={dis_r*attr, dx, dy, dz} (dis[cl] hoisted into k_edges), erecI[p]=row
__global__ void k_fill(const int* eidx, const int* flag, const float* attr, const float* dis,
                       const float* pos, int* cursor, float4* erecA, int* erecI, int E) {
  int e = blockIdx.x * 256 + threadIdx.x;
  if (e >= E) return;
  int is64 = *flag;
  int r  = load_idx(eidx, is64, e);
  int cl = load_idx(eidx, is64, (long long)E + e);
  float wr = dis[r] * attr[e];
  float dx = pos[cl * 3 + 0] - pos[r * 3 + 0];
  float dy = pos[cl * 3 + 1] - pos[r * 3 + 1];
  float dz = pos[cl * 3 + 2] - pos[r * 3 + 2];
  int p = atomicAdd(&cursor[cl], 1);
  erecA[p] = make_float4(wr, dx, dy, dz);
  erecI[p] = r;
}

// ---- shared gemm body (v7 MFMA node GEMM, see r7 notes) ----
__device__ __forceinline__ void gemm_body(
    u32* smem, int tid, int nb,
    const float* __restrict__ scalar, const float* __restrict__ vector,
    const u16* __restrict__ Wtg,
    uint4* __restrict__ rec_i4, uint4* __restrict__ rec_j4, int N) {
  u16*   Ax = (u16*)smem;
  float* Ep = (float*)smem;
  int lane = tid & 63, wv = tid >> 6;

  // ---- stage A: thread t: row = t>>2, 16 k's; convert fp32 -> bf16 hi/lo ----
  {
    int srow = tid >> 2, skq = tid & 3;
    const float* sp;
    int snode;
    if (srow < 32) { snode = nb + srow; sp = scalar + (size_t)snode * 64 + skq * 16; }
    else {
      int d = (srow - 32) >> 5, nl2 = (srow - 32) & 31;
      snode = nb + nl2;
      sp = vector + (size_t)snode * 192 + d * 64 + skq * 16;
    }
    bool valid = snode < N;
    u16 hi[16], lo[16];
    #pragma unroll
    for (int q = 0; q < 4; ++q) {
      float4 v = valid ? *(const float4*)(sp + 4 * q) : make_float4(0.f, 0.f, 0.f, 0.f);
      float xs[4] = {v.x, v.y, v.z, v.w};
      #pragma unroll
      for (int j = 0; j < 4; ++j) {
        u16 h = f2bf(xs[j]);
        hi[4 * q + j] = h;
        lo[4 * q + j] = f2bf(xs[j] - bf2f(h));
      }
    }
    int rs = srow & 7;
    #pragma unroll
    for (int c = 0; c < 2; ++c) {
      int lc = 2 * skq + c;
      uint4 wh, wl;
      wh.x = (u32)hi[8*c+0] | ((u32)hi[8*c+1] << 16);
      wh.y = (u32)hi[8*c+2] | ((u32)hi[8*c+3] << 16);
      wh.z = (u32)hi[8*c+4] | ((u32)hi[8*c+5] << 16);
      wh.w = (u32)hi[8*c+6] | ((u32)hi[8*c+7] << 16);
      wl.x = (u32)lo[8*c+0] | ((u32)lo[8*c+1] << 16);
      wl.y = (u32)lo[8*c+2] | ((u32)lo[8*c+3] << 16);
      wl.z = (u32)lo[8*c+4] | ((u32)lo[8*c+5] << 16);
      wl.w = (u32)lo[8*c+6] | ((u32)lo[8*c+7] << 16);
      *(uint4*)(Ax + srow * 128 + (lc ^ rs) * 8)        = wh;
      *(uint4*)(Ax + srow * 128 + ((8 + lc) ^ rs) * 8)  = wl;
    }
  }
  __syncthreads();

  // ---- MFMA main loop ----
  int c0 = wv * 32;
  int bl = lane & 15, bh = lane >> 4;
  f32x4 acc[8][2];
  #pragma unroll
  for (int mt = 0; mt < 8; ++mt)
    #pragma unroll
    for (int nt = 0; nt < 2; ++nt)
      acc[mt][nt] = (f32x4){0.f, 0.f, 0.f, 0.f};

  #pragma unroll
  for (int kh = 0; kh < 2; ++kh) {
    int k0 = kh * 32;
    bf16x8 Bh[2][2], Bl[2][2];
    #pragma unroll
    for (int rg = 0; rg < 2; ++rg)
      #pragma unroll
      for (int nt = 0; nt < 2; ++nt) {
        size_t rr = (size_t)(rg * 256 + c0 + nt * 16 + bl) * 128 + k0 + bh * 8;
        Bh[rg][nt] = *(const bf16x8*)(Wtg + rr);
        Bl[rg][nt] = *(const bf16x8*)(Wtg + rr + 64);
      }
    #pragma unroll
    for (int mt = 0; mt < 8; ++mt) {
      int row = mt * 16 + bl;
      int ch = (k0 >> 3) + bh, rs = row & 7;
      bf16x8 Ah = *(const bf16x8*)(Ax + row * 128 + (ch ^ rs) * 8);
      bf16x8 Al = *(const bf16x8*)(Ax + row * 128 + ((8 + ch) ^ rs) * 8);
      int rg = (mt < 2) ? 0 : 1;
      #pragma unroll
      for (int nt = 0; nt < 2; ++nt) {
        f32x4 a = acc[mt][nt];
        a = __builtin_amdgcn_mfma_f32_16x16x32_bf16(Ah, Bh[rg][nt], a, 0, 0, 0);
        a = __builtin_amdgcn_mfma_f32_16x16x32_bf16(Al, Bh[rg][nt], a, 0, 0, 0);
        a = __builtin_amdgcn_mfma_f32_16x16x32_bf16(Ah, Bl[rg][nt], a, 0, 0, 0);
        acc[mt][nt] = a;
      }
    }
  }

  // ---- epilogue: 4 passes (Gs, v0, v1, v2) through 32KB stage, pack uint4 ----
  int ech = tid & 63, eng = tid >> 6;
  uint4 oi[4], oj[4];
  #pragma unroll
  for (int pg = 0; pg < 4; ++pg) {
    __syncthreads();
    #pragma unroll
    for (int mm = 0; mm < 2; ++mm) {
      int mt = 2 * pg + mm;
      #pragma unroll
      for (int nt = 0; nt < 2; ++nt)
        #pragma unroll
        for (int r = 0; r < 4; ++r) {
          int rl = mm * 16 + bh * 4 + r;
          Ep[rl * 256 + c0 + nt * 16 + bl] = acc[mt][nt][r];
        }
    }
    __syncthreads();
    #pragma unroll
    for (int q = 0; q < 4; ++q) {
      int nl2 = eng + 8 * q;
      float vi0 = Ep[nl2 * 256 + ech];
      float vi1 = Ep[nl2 * 256 + 64 + ech];
      float vj0 = Ep[nl2 * 256 + 128 + ech];
      float vj1 = Ep[nl2 * 256 + 192 + ech];
      if (pg == 0) {
        oi[q].x = pk(vi0, vi1);                  oj[q].x = pk(vj0, vj1);
      } else if (pg == 1) {
        oi[q].y = (u32)f2bf(vi0);                oj[q].y = (u32)f2bf(vj0);
        oi[q].z = (u32)f2bf(vi1) << 16;          oj[q].z = (u32)f2bf(vj1) << 16;
      } else if (pg == 2) {
        oi[q].y |= (u32)f2bf(vi0) << 16;         oj[q].y |= (u32)f2bf(vj0) << 16;
        oi[q].w = (u32)f2bf(vi1);                oj[q].w = (u32)f2bf(vj1);
      } else {
        oi[q].z |= (u32)f2bf(vi0);               oj[q].z |= (u32)f2bf(vj0);
        oi[q].w |= (u32)f2bf(vi1) << 16;         oj[q].w |= (u32)f2bf(vj1) << 16;
      }
    }
  }
  #pragma unroll
  for (int q = 0; q < 4; ++q) {
    int node = nb + eng + 8 * q;
    if (node < N) {
      rec_i4[(size_t)node * 64 + ech] = oi[q];
      rec_j4[(size_t)node * 64 + ech] = oj[q];
    }
  }
}

// ---- fused kernel: full gemm + degree atomics (independent work co-scheduled) ----
__global__ __launch_bounds__(512, 4) void k_gemm_deg(
    const float* __restrict__ scalar, const float* __restrict__ vector,
    const u16* __restrict__ Wtg,
    uint4* __restrict__ rec_i4, uint4* __restrict__ rec_j4, int N, int GB,
    const int* __restrict__ eidx, const int* __restrict__ flag,
    const float* __restrict__ attr, double* __restrict__ dpk, int E) {
  __shared__ u32 smem[8192];
  int tid = threadIdx.x;
  if ((int)blockIdx.x >= GB) {
    int e = ((int)blockIdx.x - GB) * 512 + tid;
    if (e < E) {
      int is64 = *flag;
      int col = load_idx(eidx, is64, (long long)E + e);
      atomicAdd(&dpk[col], (double)attr[e] + CNTSC);
    }
    return;
  }
  gemm_body(smem, tid, (int)blockIdx.x * 32, scalar, vector, Wtg, rec_i4, rec_j4, N);
}

// Fused hot kernel: one wave per node, wave-uniform scalar edge metadata held in
// SGPRs (rowptr/erecI/erecA indices readfirstlane'd -> scalar loads), 2-edge
// unrolled loop with double prefetch, d-fused in-wave epilogue matvecs.
__global__ __launch_bounds__(512) void k_edges(
    const u16* __restrict__ rec_i, const u16* __restrict__ rec_j,
    const float4* __restrict__ erecA, const int* __restrict__ erecI,
    const int* __restrict__ rowptr, const float* __restrict__ dis,
    const float* __restrict__ scalar, const float* __restrict__ vector,
    const float* __restrict__ bss, const float* __restrict__ bvs,
    const float* __restrict__ bsv, const float* __restrict__ bsl,
    const u32* __restrict__ Wsl2g, const u32* __restrict__ Wpkg,
    const float* __restrict__ bcg,
    float* __restrict__ out_s, float* __restrict__ out_v, int N) {
  __shared__ u32 sWsl[4096];        // 16 KB
  __shared__ u32 sWv[2048];         // 8 KB  (Wvl_right only)
  __shared__ float sStage[8 * 192]; // 6 KB, wave-private epilogue stage
  int tid = threadIdx.x, lane = tid & 63, wv = tid >> 6;
  for (int o = tid; o < 4096; o += 512) sWsl[o] = Wsl2g[o];
  for (int o = tid; o < 2048; o += 512) sWv[o] = Wpkg[o];
  __syncthreads();   // the only block barrier

  int node = __builtin_amdgcn_readfirstlane((int)(blockIdx.x * 8) + wv);
  if (node >= N) node = N - 1;

  uint4 riv = *(const uint4*)(rec_i + ((size_t)node << 9) + lane * 8);
  float aiB  = lo16(riv.x) + bss[lane];
  float KciB = TWOL2E * (hi16(riv.x) + bsv[lane]);
  float Bvs  = bvs[lane];
  float bib0 = lo16(riv.y) + Bvs;
  float bib1 = hi16(riv.y) + Bvs;
  float bib2 = lo16(riv.z) + Bvs;
  float Pi0  = hi16(riv.z), Pi1 = lo16(riv.w), Pi2 = hi16(riv.w);
  float bsl_c = bsl[lane], bc_c = bcg[lane];
  float disc = dis[node];

  float us = 0, uv = 0, t0 = 0, t1 = 0, t2 = 0, g0 = 0, g1 = 0, g2 = 0, wa = 0;
  // wave-uniform CSR bounds in SGPRs -> uniform (scalar) loads downstream
  int rp = __builtin_amdgcn_readfirstlane(rowptr[node]);
  int re = __builtin_amdgcn_readfirstlane(rowptr[node + 1]);
  u32 lane16 = (u32)lane << 4;
  const char* rjb = (const char*)rec_j;

  // erecI has 64 zeroed ints of slack past E -> prefetch reads always valid
  u32 ra = (u32)__builtin_amdgcn_readfirstlane(erecI[rp]);
  u32 rb = (u32)__builtin_amdgcn_readfirstlane(erecI[rp + 1]);
  uint4 pre0 = *(const uint4*)(rjb + ((ra << 10) + lane16));
  uint4 pre1 = *(const uint4*)(rjb + ((rb << 10) + lane16));
  int p = rp;
  #define EDGE_MATH(CUR, EV)                                                  \
    {                                                                         \
      float nrm = EV.x, dx = EV.y, dy = EV.z, dz = EV.w;                      \
      float aj  = lo16(CUR.x), cj  = hi16(CUR.x);                             \
      float bj0 = lo16(CUR.y), bj1 = hi16(CUR.y), bj2 = lo16(CUR.z);          \
      float rj0 = hi16(CUR.z), rj1 = lo16(CUR.w), rj2 = hi16(CUR.w);          \
      float xs  = aiB + aj;                                                   \
      float s2s = xs * frcp(1.f + fexp2(xs * NL2E));                          \
      float yv  = (bib0 + bj0) * dx;                                          \
      yv = fmaf(bib1 + bj1, dy, yv);                                          \
      yv = fmaf(bib2 + bj2, dz, yv);                                          \
      float v2s = yv * frcp(1.f + fexp2(yv * NL2E));                          \
      float qh  = fmaf(TWOL2E, cj, KciB);                                     \
      float th0 = fmaf(-2.f, frcp(1.f + fexp2(qh * dx)), 1.f);                \
      float th1 = fmaf(-2.f, frcp(1.f + fexp2(qh * dy)), 1.f);                \
      float th2 = fmaf(-2.f, frcp(1.f + fexp2(qh * dz)), 1.f);                \
      us = fmaf(nrm, s2s, us); uv = fmaf(nrm, v2s, uv);                       \
      t0 = fmaf(nrm, th0, t0); t1 = fmaf(nrm, th1, t1); t2 = fmaf(nrm, th2, t2);\
      g0 = fmaf(nrm, rj0, g0); g1 = fmaf(nrm, rj1, g1); g2 = fmaf(nrm, rj2, g2);\
      wa += nrm;                                                              \
    }
  for (; p + 1 < re; p += 2) {
    uint4 cur0 = pre0, cur1 = pre1;
    u32 rn0 = (u32)__builtin_amdgcn_readfirstlane(erecI[p + 2]);
    u32 rn1 = (u32)__builtin_amdgcn_readfirstlane(erecI[p + 3]);
    pre0 = *(const uint4*)(rjb + ((rn0 << 10) + lane16));
    pre1 = *(const uint4*)(rjb + ((rn1 << 10) + lane16));
    float4 e0 = erecA[p];
    float4 e1 = erecA[p + 1];
    EDGE_MATH(cur0, e0)
    EDGE_MATH(cur1, e1)
  }
  if (p < re) {
    uint4 cur0 = pre0;
    float4 e0 = erecA[p];
    EDGE_MATH(cur0, e0)
  }
  #undef EDGE_MATH

  // scale by the wave-uniform dis[node] (hoisted out of per-edge nrm)
  us *= disc; uv *= disc;
  t0 *= disc; t1 *= disc; t2 *= disc;
  g0 *= disc; g1 *= disc; g2 *= disc;
  wa *= disc;

  // ---- epilogue: scalar head (wave-local, no block barrier) ----
  float* mys = &sStage[wv * 192];
  mys[lane] = us; mys[64 + lane] = uv;
  __threadfence_block();
  float acc = wa * bsl_c;
  #pragma unroll
  for (int g = 0; g < 32; ++g) {
    float4 u = *(const float4*)&mys[4 * g];
    uint2 w = *(const uint2*)&sWsl[(g * 64 + lane) * 2];
    acc = fmaf(u.x, lo16(w.x), acc);
    acc = fmaf(u.y, hi16(w.x), acc);
    acc = fmaf(u.z, lo16(w.y), acc);
    acc = fmaf(u.w, hi16(w.y), acc);
  }
  size_t so = ((size_t)node << 6) + lane;
  out_s[so] = acc * frcp(1.f + fexp2(acc * NL2E)) + scalar[so];

  // ---- epilogue: vector head, d-fused (one pass over sWv, 3 accumulators) ----
  __threadfence_block();
  mys[lane] = t0; mys[64 + lane] = t1; mys[128 + lane] = t2;
  __threadfence_block();
  float a20 = fmaf(wa, bc_c + Pi0, g0);
  float a21 = fmaf(wa, bc_c + Pi1, g1);
  float a22 = fmaf(wa, bc_c + Pi2, g2);
  #pragma unroll
  for (int g = 0; g < 16; ++g) {
    float4 u0 = *(const float4*)&mys[4 * g];
    float4 u1 = *(const float4*)&mys[64 + 4 * g];
    float4 u2 = *(const float4*)&mys[128 + 4 * g];
    uint2 w = *(const uint2*)&sWv[(g * 64 + lane) * 2];
    float w0 = lo16(w.x), w1 = hi16(w.x), w2 = lo16(w.y), w3 = hi16(w.y);
    a20 = fmaf(u0.x, w0, a20); a20 = fmaf(u0.y, w1, a20);
    a20 = fmaf(u0.z, w2, a20); a20 = fmaf(u0.w, w3, a20);
    a21 = fmaf(u1.x, w0, a21); a21 = fmaf(u1.y, w1, a21);
    a21 = fmaf(u1.z, w2, a21); a21 = fmaf(u1.w, w3, a21);
    a22 = fmaf(u2.x, w0, a22); a22 = fmaf(u2.y, w1, a22);
    a22 = fmaf(u2.z, w2, a22); a22 = fmaf(u2.w, w3, a22);
  }
  float a2v[3] = {a20, a21, a22};
  #pragma unroll
  for (int d = 0; d < 3; ++d) {
    size_t vo = (((size_t)node * 3 + d) << 6) + lane;
    float th = fmaf(-2.f, frcp(1.f + fexp2(TWOL2E * a2v[d])), 1.f);
    out_v[vo] = th + vector[vo];
  }
}

extern "C" void kernel_launch(void* const* d_in, const int* in_sizes, int n_in,
                              void* d_out, int out_size, void* d_ws, size_t ws_size,
                              hipStream_t stream) {
  const float* scalar   = (const float*)d_in[0];
  const float* vector   = (const float*)d_in[1];
  const float* position = (const float*)d_in[2];
  const int*   eidx     = (const int*)d_in[3];
  const float* attr     = (const float*)d_in[4];
  const float* Wss = (const float*)d_in[5];
  const float* bss = (const float*)d_in[6];
  const float* Wvs = (const float*)d_in[7];
  const float* bvs = (const float*)d_in[8];
  const float* Wsl = (const float*)d_in[9];
  const float* bsl = (const float*)d_in[10];
  const float* Wsv = (const float*)d_in[11];
  const float* bsv = (const float*)d_in[12];
  const float* Wvv = (const float*)d_in[13];
  const float* bvv = (const float*)d_in[14];
  const float* Wvl = (const float*)d_in[15];
  const float* bvl = (const float*)d_in[16];

  int N = in_sizes[0] / 64;
  int E = in_sizes[4];
  int NB = (N + 255) / 256;   // scan tiles

  char* wsb = (char*)d_ws;
  size_t off = 0;
  auto alloc = [&](size_t bytes) -> char* {
    char* p = wsb + off;
    off += (bytes + 255) & ~(size_t)255;
    return p;
  };
  double* dpk    = (double*)alloc((size_t)N * 8);
  int*    rowptr = (int*)alloc((size_t)(N + 1) * 4);
  int*    cursor = (int*)alloc((size_t)N * 4);
  float*  dis    = (float*)alloc((size_t)N * 4);
  int*    tilestat = (int*)alloc((size_t)NB * 4);
  int*    tilectr  = (int*)alloc(4);
  float4* erecA  = (float4*)alloc((size_t)E * 16);
  int*    erecI  = (int*)alloc((size_t)(E + 64) * 4);   // +slack for prefetch reads
  u16*    rec_i  = (u16*)alloc((size_t)N * 512 * 2);
  u16*    rec_j  = (u16*)alloc((size_t)N * 512 * 2);
  u16*    Wtg    = (u16*)alloc(512 * 128 * 2);          // 128 KB split-bf16 W^T
  u32*    Wsl2   = (u32*)alloc(4096 * 4);
  u32*    Wpk    = (u32*)alloc(2048 * 4);
  float*  WcTmp  = (float*)alloc(64 * 128 * 4);
  float*  bc     = (float*)alloc(64 * 4);
  int*    flag   = (int*)alloc(4);
  (void)ws_size; (void)n_in; (void)out_size;

  int GB = (N + 31) / 32;     // gemm blocks
  int DB = (E + 511) / 512;   // deg blocks

  k_prep1<<<35 + NB, 256, 0, stream>>>(Wvl, Wvv, bvv, bvl, eidx, E, flag,
                                       WcTmp, bc, dpk, erecI, tilestat, tilectr, N, NB);
  k_prep2<<<11, 256, 0, stream>>>(Wss, Wsv, Wvs, Wsl, Wvl, WcTmp, Wsl2, Wpk, Wtg);
  k_gemm_deg<<<GB + DB, 512, 0, stream>>>(scalar, vector, Wtg,
                                          (uint4*)rec_i, (uint4*)rec_j, N, GB,
                                          eidx, flag, attr, dpk, E);
  k_scan<<<NB, 256, 0, stream>>>(dpk, dis, rowptr, cursor, tilestat, tilectr, N, E);
  k_fill<<<(E + 255) / 256, 256, 0, stream>>>(eidx, flag, attr, dis, position, cursor, erecA, erecI, E);
  k_edges<<<(N + 7) / 8, 512, 0, stream>>>(rec_i, rec_j, erecA, erecI, rowptr, dis,
                                           scalar, vector, bss, bvs, bsv, bsl,
                                           Wsl2, Wpk, bc,
                                           (float*)d_out, (float*)d_out + (size_t)N * 64, N);
}